// Round 5
// baseline (378.229 us; speedup 1.0000x reference)
//
#include <hip/hip_runtime.h>

#define NPOSTS 2048
#define SEQ 64
#define W2V 300
#define NH 5
#define HD 60
#define S2VD 256
#define HIDD 256
#define NEDGE 2047
#define UDIM 1500

// ================= Stage 0a: WsWo = Ws@Wo [256x300]; bias3A = bs + Ws@bo =================
__global__ __launch_bounds__(320) void k_wfoldA(
    const float* __restrict__ Ws, const float* __restrict__ Wo,
    const float* __restrict__ bo, const float* __restrict__ bs,
    float* __restrict__ WsWo, float* __restrict__ bias3A)
{
    const int r0 = blockIdx.x * 16;
    const int tid = threadIdx.x;
    __shared__ float sT[W2V][16];   // sT[k][r] = Ws[r0+r][k]
    for (int i = tid; i < 16 * W2V; i += 320) {
        int r = i / W2V, k = i % W2V;
        sT[k][r] = Ws[(size_t)(r0 + r) * W2V + k];
    }
    __syncthreads();
    if (tid <= W2V) {
        float a[16];
        #pragma unroll
        for (int r = 0; r < 16; ++r) a[r] = 0.f;
        for (int k = 0; k < W2V; ++k) {
            float wv = (tid < W2V) ? Wo[(size_t)k * W2V + tid] : bo[k];
            const float4* s4 = reinterpret_cast<const float4*>(&sT[k][0]);
            float4 q0 = s4[0], q1 = s4[1], q2 = s4[2], q3 = s4[3];
            float qq[16] = {q0.x,q0.y,q0.z,q0.w, q1.x,q1.y,q1.z,q1.w,
                            q2.x,q2.y,q2.z,q2.w, q3.x,q3.y,q3.z,q3.w};
            #pragma unroll
            for (int r = 0; r < 16; ++r) a[r] = fmaf(wv, qq[r], a[r]);
        }
        if (tid < W2V) {
            #pragma unroll
            for (int r = 0; r < 16; ++r) WsWo[(size_t)(r0 + r) * W2V + tid] = a[r];
        } else {
            #pragma unroll
            for (int r = 0; r < 16; ++r) bias3A[r0 + r] = bs[r0 + r] + a[r];
        }
    }
}

// ===== Stage 0b: Wfold[t][h*300+c] = sum_d WsWo[t][h*60+d]*Wv[600+h*60+d][c]; bpart = WsWo_h@bv_h =====
__global__ __launch_bounds__(320) void k_wfold2(
    const float* __restrict__ WsWo, const float* __restrict__ Wqkv, const float* __restrict__ bqkv,
    float* __restrict__ Wfold, float* __restrict__ bpart)
{
    const int r0 = blockIdx.x * 16;
    const int h = blockIdx.y;
    const int tid = threadIdx.x;
    __shared__ float sT[HD][16];    // sT[d][r] = WsWo[r0+r][h*60+d]
    for (int i = tid; i < 16 * HD; i += 320) {
        int r = i / HD, d = i % HD;
        sT[d][r] = WsWo[(size_t)(r0 + r) * W2V + h * HD + d];
    }
    __syncthreads();
    if (tid <= W2V) {
        float a[16];
        #pragma unroll
        for (int r = 0; r < 16; ++r) a[r] = 0.f;
        for (int d = 0; d < HD; ++d) {
            float wv = (tid < W2V) ? Wqkv[(size_t)(2 * W2V + h * HD + d) * W2V + tid]
                                   : bqkv[2 * W2V + h * HD + d];
            const float4* s4 = reinterpret_cast<const float4*>(&sT[d][0]);
            float4 q0 = s4[0], q1 = s4[1], q2 = s4[2], q3 = s4[3];
            float qq[16] = {q0.x,q0.y,q0.z,q0.w, q1.x,q1.y,q1.z,q1.w,
                            q2.x,q2.y,q2.z,q2.w, q3.x,q3.y,q3.z,q3.w};
            #pragma unroll
            for (int r = 0; r < 16; ++r) a[r] = fmaf(wv, qq[r], a[r]);
        }
        if (tid < W2V) {
            #pragma unroll
            for (int r = 0; r < 16; ++r)
                Wfold[(size_t)(r0 + r) * UDIM + h * W2V + tid] = a[r];
        } else {
            #pragma unroll
            for (int r = 0; r < 16; ++r) bpart[h * S2VD + r0 + r] = a[r];
        }
    }
}

// ================= Stage 1a: Q = Emb0 @ Wq^T + bq  (8 posts/block) =================
__global__ __launch_bounds__(320) void k_q(
    const int* __restrict__ nodeText, const float* __restrict__ embed_w,
    const float* __restrict__ Wqkv, const float* __restrict__ bqkv,
    float* __restrict__ Qout)
{
    const int r0 = blockIdx.x * 8;
    const int tid = threadIdx.x;
    __shared__ int stok[8];
    __shared__ float sE[8][W2V];
    if (tid < 8) stok[tid] = nodeText[(size_t)(r0 + tid) * SEQ];
    __syncthreads();
    for (int i = tid; i < 8 * 75; i += 320) {
        int r = i / 75, c4 = i % 75;
        *reinterpret_cast<float4*>(&sE[r][c4 * 4]) =
            *reinterpret_cast<const float4*>(embed_w + (size_t)stok[r] * W2V + c4 * 4);
    }
    __syncthreads();
    if (tid < W2V) {
        const float4* w4p = reinterpret_cast<const float4*>(Wqkv + (size_t)tid * W2V);
        float b = bqkv[tid];
        float a[8];
        #pragma unroll
        for (int r = 0; r < 8; ++r) a[r] = b;
        for (int c4 = 0; c4 < 75; ++c4) {
            float4 w4 = w4p[c4];
            #pragma unroll
            for (int r = 0; r < 8; ++r) {
                float4 v = *reinterpret_cast<const float4*>(&sE[r][c4 * 4]);
                a[r] = fmaf(w4.x, v.x, a[r]);
                a[r] = fmaf(w4.y, v.y, a[r]);
                a[r] = fmaf(w4.z, v.z, a[r]);
                a[r] = fmaf(w4.w, v.w, a[r]);
            }
        }
        #pragma unroll
        for (int r = 0; r < 8; ++r) Qout[(size_t)(r0 + r) * W2V + tid] = a[r];
    }
}

// ================= Stage 1b: u[p][h*300+c] = sum_d Q[p][h*60+d] * Wk[300+h*60+d][c] =================
__global__ __launch_bounds__(320) void k_u(
    const float* __restrict__ Q, const float* __restrict__ Wqkv, float* __restrict__ uout)
{
    const int r0 = blockIdx.x * 16;
    const int h = blockIdx.y;
    const int tid = threadIdx.x;
    __shared__ float sT[HD][16];   // sT[d][r] = Q[r0+r][h*60+d]
    for (int i = tid; i < 16 * HD; i += 320) {
        int r = i / HD, d = i % HD;
        sT[d][r] = Q[(size_t)(r0 + r) * W2V + h * HD + d];
    }
    __syncthreads();
    if (tid < W2V) {
        float a[16];
        #pragma unroll
        for (int r = 0; r < 16; ++r) a[r] = 0.f;
        for (int d = 0; d < HD; ++d) {
            float wv = Wqkv[(size_t)(W2V + h * HD + d) * W2V + tid];   // coalesced
            const float4* s4 = reinterpret_cast<const float4*>(&sT[d][0]);
            float4 q0 = s4[0], q1 = s4[1], q2 = s4[2], q3 = s4[3];
            float qq[16] = {q0.x,q0.y,q0.z,q0.w, q1.x,q1.y,q1.z,q1.w,
                            q2.x,q2.y,q2.z,q2.w, q3.x,q3.y,q3.z,q3.w};
            #pragma unroll
            for (int r = 0; r < 16; ++r) a[r] = fmaf(wv, qq[r], a[r]);
        }
        #pragma unroll
        for (int r = 0; r < 16; ++r)
            uout[(size_t)(r0 + r) * UDIM + h * W2V + tid] = a[r];
    }
}

// ================= Stage 1c: scores + softmax + e (1 post/block, LDS-staged Emb) =================
__global__ __launch_bounds__(384) void k_att(
    const int* __restrict__ nodeText, const float* __restrict__ embed_w,
    float* __restrict__ ue)
{
    __shared__ float sE[SEQ][W2V];     // 76.8 KB; stride 75 float4 (odd) -> conflict-free both ways
    __shared__ float satt[NH][SEQ];
    __shared__ int   stoks[SEQ];

    const int p = blockIdx.x;
    const int tid = threadIdx.x;

    if (tid < SEQ) stoks[tid] = nodeText[(size_t)p * SEQ + tid];
    __syncthreads();

    for (int i = tid; i < SEQ * 75; i += 384) {
        int r = i / 75, c4 = i % 75;
        *reinterpret_cast<float4*>(&sE[r][c4 * 4]) =
            *reinterpret_cast<const float4*>(embed_w + (size_t)stoks[r] * W2V + c4 * 4);
    }
    __syncthreads();

    // scores: wave h = head h, lane j = token j; u read wave-uniform from global
    if (tid < NH * SEQ) {
        const int h = tid >> 6, j = tid & 63;
        const float4* u4 = reinterpret_cast<const float4*>(ue + (size_t)p * UDIM + h * W2V);
        const float4* e4 = reinterpret_cast<const float4*>(&sE[j][0]);
        float acc = 0.f;
        #pragma unroll 5
        for (int c4 = 0; c4 < 75; ++c4) {
            float4 uv = u4[c4];
            float4 ev = e4[c4];
            acc = fmaf(uv.x, ev.x, acc);
            acc = fmaf(uv.y, ev.y, acc);
            acc = fmaf(uv.z, ev.z, acc);
            acc = fmaf(uv.w, ev.w, acc);
        }
        // scores bounded |s| << 1 (0.02-scale weights) -> exp safe without max-subtract
        float ex = expf(acc * 0.12909944487358056f);
        float l = ex;
        #pragma unroll
        for (int off = 32; off > 0; off >>= 1) l += __shfl_xor(l, off);
        satt[h][j] = ex / l;
    }
    __syncthreads();

    // e[h][c] = sum_j att[h][j] * Emb[j][c]
    if (tid < NH * 75) {
        const int h = tid / 75, c4 = tid % 75;
        float4 a = make_float4(0.f, 0.f, 0.f, 0.f);
        #pragma unroll 4
        for (int j = 0; j < SEQ; ++j) {
            float av = satt[h][j];
            float4 ev = *reinterpret_cast<const float4*>(&sE[j][c4 * 4]);
            a.x = fmaf(av, ev.x, a.x);
            a.y = fmaf(av, ev.y, a.y);
            a.z = fmaf(av, ev.z, a.z);
            a.w = fmaf(av, ev.w, a.w);
        }
        *reinterpret_cast<float4*>(ue + (size_t)p * UDIM + h * W2V + c4 * 4) = a;
    }
}

// ================= Stage 1d: s2v = tanh(Wfold @ e + bias3)  (8 posts/block, K=1500) =================
__global__ __launch_bounds__(256) void k_s2v(
    const float* __restrict__ e, const float* __restrict__ Wfold,
    const float* __restrict__ bias3A, const float* __restrict__ bpart,
    float* __restrict__ s2v_out)
{
    const int r0 = blockIdx.x * 8;
    const int t = threadIdx.x;
    __shared__ float se[8][W2V];
    float a[8];
    #pragma unroll
    for (int r = 0; r < 8; ++r) a[r] = 0.f;
    const float bias = bias3A[t] + bpart[t] + bpart[256 + t] + bpart[512 + t]
                     + bpart[768 + t] + bpart[1024 + t];
    const float4* w4p = reinterpret_cast<const float4*>(Wfold + (size_t)t * UDIM);
    for (int ch = 0; ch < 5; ++ch) {
        __syncthreads();
        for (int i = t; i < 8 * 75; i += 256) {
            int r = i / 75, c4 = i % 75;
            *reinterpret_cast<float4*>(&se[r][c4 * 4]) =
                *reinterpret_cast<const float4*>(e + (size_t)(r0 + r) * UDIM + ch * W2V + c4 * 4);
        }
        __syncthreads();
        for (int c4 = 0; c4 < 75; ++c4) {
            float4 w4 = w4p[ch * 75 + c4];
            #pragma unroll
            for (int r = 0; r < 8; ++r) {
                float4 v = *reinterpret_cast<const float4*>(&se[r][c4 * 4]);
                a[r] = fmaf(w4.x, v.x, a[r]);
                a[r] = fmaf(w4.y, v.y, a[r]);
                a[r] = fmaf(w4.z, v.z, a[r]);
                a[r] = fmaf(w4.w, v.w, a[r]);
            }
        }
    }
    #pragma unroll
    for (int r = 0; r < 8; ++r)
        s2v_out[(size_t)(r0 + r) * S2VD + t] = tanhf(a[r] + bias);
}

// ================= Stage 2: GCN branches (blockIdx.y = branch: 0=TD, 1=BU) =================

__global__ __launch_bounds__(256) void k_deg(
    const int* __restrict__ eiTD, const int* __restrict__ eiBU, int* __restrict__ deg)
{
    const int b = blockIdx.y;
    const int* ei = b ? eiBU : eiTD;
    int e = blockIdx.x * 256 + threadIdx.x;
    if (e < NEDGE) atomicAdd(&deg[b * NPOSTS + ei[NEDGE + e]], 1);
}

__global__ __launch_bounds__(256) void k_gemm1(
    const float* __restrict__ x, const float* __restrict__ wtd, const float* __restrict__ wbu,
    const float* __restrict__ btd, const float* __restrict__ bbu, const int* __restrict__ deg,
    float* __restrict__ hout, float* __restrict__ cout_)
{
    const int b = blockIdx.y;
    const float* w = b ? wbu : wtd;
    const float* bias = b ? bbu : btd;
    float* hb = hout + (size_t)b * NPOSTS * HIDD;
    float* cb = cout_ + (size_t)b * NPOSTS * HIDD;
    const int* dg = deg + b * NPOSTS;
    const int r0 = blockIdx.x * 16;
    const int tid = threadIdx.x;
    __shared__ float sx[16][S2VD];
    for (int i = tid; i < 16 * S2VD; i += 256)
        sx[i / S2VD][i % S2VD] = x[(size_t)(r0 + i / S2VD) * S2VD + (i % S2VD)];
    __syncthreads();
    float acc[16];
    #pragma unroll
    for (int r = 0; r < 16; ++r) acc[r] = 0.f;
    const float4* wr4 = reinterpret_cast<const float4*>(w + (size_t)tid * S2VD);
    for (int c4 = 0; c4 < 64; ++c4) {
        float4 w4 = wr4[c4];
        #pragma unroll
        for (int r = 0; r < 16; ++r) {
            const float4 v = *reinterpret_cast<const float4*>(&sx[r][c4 * 4]);
            acc[r] = fmaf(w4.x, v.x, acc[r]);
            acc[r] = fmaf(w4.y, v.y, acc[r]);
            acc[r] = fmaf(w4.z, v.z, acc[r]);
            acc[r] = fmaf(w4.w, v.w, acc[r]);
        }
    }
    float bv = bias[tid];
    #pragma unroll
    for (int r = 0; r < 16; ++r) {
        int n = r0 + r;
        float dinv = 1.f / (float)(dg[n] + 1);
        hb[(size_t)n * HIDD + tid] = acc[r];
        cb[(size_t)n * HIDD + tid] = bv + acc[r] * dinv;
    }
}

__global__ __launch_bounds__(256) void k_gemm2(
    const float* __restrict__ c1, const float* __restrict__ w2td, const float* __restrict__ w2bu,
    const float* __restrict__ btd, const float* __restrict__ bbu, const int* __restrict__ deg,
    const float* __restrict__ rootv, float* __restrict__ hout, float* __restrict__ cout_)
{
    const int b = blockIdx.y;
    const float* w = b ? w2bu : w2td;
    const float* bias = b ? bbu : btd;
    const float* xin = c1 + (size_t)b * NPOSTS * HIDD;
    float* hb = hout + (size_t)b * NPOSTS * HIDD;
    float* cb = cout_ + (size_t)b * NPOSTS * HIDD;
    const int* dg = deg + b * NPOSTS;
    const int r0 = blockIdx.x * 16;
    const int tid = threadIdx.x;
    __shared__ float sx[16][HIDD];
    for (int i = tid; i < 16 * HIDD; i += 256)
        sx[i / HIDD][i % HIDD] = fmaxf(xin[(size_t)(r0 + i / HIDD) * HIDD + (i % HIDD)], 0.f);
    __syncthreads();
    float acc[16];
    const float rv = rootv[b * HIDD + tid];
    #pragma unroll
    for (int r = 0; r < 16; ++r) acc[r] = rv;
    const float4* wr4 = reinterpret_cast<const float4*>(w + (size_t)tid * 512);
    for (int c4 = 0; c4 < 64; ++c4) {
        float4 w4 = wr4[c4];
        #pragma unroll
        for (int r = 0; r < 16; ++r) {
            const float4 v = *reinterpret_cast<const float4*>(&sx[r][c4 * 4]);
            acc[r] = fmaf(w4.x, v.x, acc[r]);
            acc[r] = fmaf(w4.y, v.y, acc[r]);
            acc[r] = fmaf(w4.z, v.z, acc[r]);
            acc[r] = fmaf(w4.w, v.w, acc[r]);
        }
    }
    float bv = bias[tid];
    #pragma unroll
    for (int r = 0; r < 16; ++r) {
        int n = r0 + r;
        float dinv = 1.f / (float)(dg[n] + 1);
        hb[(size_t)n * HIDD + tid] = acc[r];
        cb[(size_t)n * HIDD + tid] = bv + acc[r] * dinv;
    }
}

__global__ __launch_bounds__(256) void k_scat(
    const int* __restrict__ eiTD, const int* __restrict__ eiBU,
    const float* __restrict__ h, const int* __restrict__ deg, float* __restrict__ cacc)
{
    const int b = blockIdx.y, e = blockIdx.x, tid = threadIdx.x;
    const int* ei = b ? eiBU : eiTD;
    const int s = ei[e], d = ei[NEDGE + e];
    const int* dg = deg + b * NPOSTS;
    float norm = rsqrtf((float)(dg[s] + 1)) * rsqrtf((float)(dg[d] + 1));
    const float* hb = h + (size_t)b * NPOSTS * HIDD;
    float* cb = cacc + (size_t)b * NPOSTS * HIDD;
    atomicAdd(&cb[(size_t)d * HIDD + tid], norm * hb[(size_t)s * HIDD + tid]);
}

__global__ __launch_bounds__(256) void k_root(
    const float* __restrict__ s2v, const float* __restrict__ c1,
    const float* __restrict__ w2td, const float* __restrict__ w2bu,
    const int* __restrict__ rootPtr, float* __restrict__ rootv, float* __restrict__ c1root)
{
    const int b = blockIdx.y, tid = threadIdx.x;
    const float* w2 = b ? w2bu : w2td;
    const int root = rootPtr[0];
    __shared__ float sx[S2VD];
    sx[tid] = fmaxf(s2v[(size_t)root * S2VD + tid], 0.f);
    __syncthreads();
    const float* cb = c1 + (size_t)b * NPOSTS * HIDD;
    c1root[b * HIDD + tid] = cb[(size_t)root * HIDD + tid];
    const float* wr = w2 + (size_t)tid * 512 + 256;
    float acc = 0.f;
    #pragma unroll 4
    for (int c = 0; c < S2VD; ++c) acc = fmaf(wr[c], sx[c], acc);
    rootv[b * HIDD + tid] = acc;
}

__global__ __launch_bounds__(256) void k_reduce(
    const float* __restrict__ cacc, float* __restrict__ msum)
{
    const int b = blockIdx.y, tid = threadIdx.x;
    const int base = blockIdx.x * 32;
    const float* cb = cacc + (size_t)b * NPOSTS * HIDD;
    float local = 0.f;
    #pragma unroll 4
    for (int r = 0; r < 32; ++r) local += fmaxf(cb[(size_t)(base + r) * HIDD + tid], 0.f);
    atomicAdd(&msum[b * HIDD + tid], local);
}

__global__ __launch_bounds__(256) void k_final(
    const float* __restrict__ c1root, const float* __restrict__ msum,
    const float* __restrict__ fc_w, const float* __restrict__ fc_b, float* __restrict__ outp)
{
    const int tid = threadIdx.x;
    __shared__ float sf[1024];
    for (int k = tid; k < 1024; k += 256) {
        int seg = k >> 8, idx = k & 255;
        float v;
        if (seg == 0)      v = c1root[idx];
        else if (seg == 1) v = msum[idx] * (1.f / (float)NPOSTS);
        else if (seg == 2) v = c1root[256 + idx];
        else               v = msum[256 + idx] * (1.f / (float)NPOSTS);
        sf[k] = v;
    }
    __syncthreads();
    const int t = tid >> 6, lane = tid & 63;
    float part = 0.f;
    for (int k = lane; k < 1024; k += 64) part = fmaf(fc_w[t * 1024 + k], sf[k], part);
    #pragma unroll
    for (int off = 32; off > 0; off >>= 1) part += __shfl_down(part, off);
    if (lane == 0) outp[t] = part + fc_b[t];
}

extern "C" void kernel_launch(void* const* d_in, const int* in_sizes, int n_in,
                              void* d_out, int out_size, void* d_ws, size_t ws_size,
                              hipStream_t stream) {
    (void)in_sizes; (void)n_in; (void)out_size; (void)ws_size;

    const int*   nodeText   = (const int*)d_in[0];
    const int*   eiTD       = (const int*)d_in[1];
    const int*   eiBU       = (const int*)d_in[2];
    const int*   threadIdxP = (const int*)d_in[3];
    const float* embed_w    = (const float*)d_in[5];
    const float* in_proj_w  = (const float*)d_in[6];
    const float* in_proj_b  = (const float*)d_in[7];
    const float* out_proj_w = (const float*)d_in[8];
    const float* out_proj_b = (const float*)d_in[9];
    const float* s2v_w      = (const float*)d_in[10];
    const float* s2v_b      = (const float*)d_in[11];
    const float* td_w1      = (const float*)d_in[12];
    const float* td_b1      = (const float*)d_in[13];
    const float* td_w2      = (const float*)d_in[14];
    const float* td_b2      = (const float*)d_in[15];
    const float* bu_w1      = (const float*)d_in[16];
    const float* bu_b1      = (const float*)d_in[17];
    const float* bu_w2      = (const float*)d_in[18];
    const float* bu_b2      = (const float*)d_in[19];
    const float* fc_w       = (const float*)d_in[20];
    const float* fc_b       = (const float*)d_in[21];
    float* outp = (float*)d_out;

    // workspace layout
    char* w = (char*)d_ws;
    int*   deg    = (int*)w;                                          // 16384 B
    float* msum   = (float*)(w + 16384);                              // 2048 B
    float* rootv  = (float*)(w + 16384 + 2048);
    float* c1root = (float*)(w + 16384 + 4096);
    float* s2v    = (float*)(w + 24576);                              // 2 MB
    float* hbuf   = (float*)(w + 24576 + 2097152);                    // 4 MB
    float* cbuf   = (float*)(w + 24576 + 2097152 + 4194304);          // 4 MB
    float* Qbuf   = (float*)(w + 24576 + 2097152 + 4194304 + 4194304);             // 2.46 MB
    float* uebuf  = (float*)(w + 24576 + 2097152 + 4194304 + 4194304 + 2457600);   // 12.29 MB

    // folded-weight buffers alias hbuf/cbuf (consumed before k_gemm1 writes them)
    float* Wfold  = hbuf;                 // 256*1500 floats = 1.536 MB
    float* WsWo   = cbuf;                 // 256*300 floats
    float* bias3A = cbuf + 256 * 300;     // 256 floats
    float* bpart  = bias3A + 256;         // 5*256 floats

    hipMemsetAsync(d_ws, 0, 16384 + 2048, stream);

    // ---- independent prep ----
    k_deg<<<dim3((NEDGE + 255) / 256, 2), 256, 0, stream>>>(eiTD, eiBU, deg);
    k_wfoldA<<<16, 320, 0, stream>>>(s2v_w, out_proj_w, out_proj_b, s2v_b, WsWo, bias3A);
    k_wfold2<<<dim3(16, 5), 320, 0, stream>>>(WsWo, in_proj_w, in_proj_b, Wfold, bpart);

    // ---- stage 1 ----
    k_q  <<<NPOSTS / 8, 320, 0, stream>>>(nodeText, embed_w, in_proj_w, in_proj_b, Qbuf);
    k_u  <<<dim3(NPOSTS / 16, 5), 320, 0, stream>>>(Qbuf, in_proj_w, uebuf);
    k_att<<<NPOSTS, 384, 0, stream>>>(nodeText, embed_w, uebuf);
    k_s2v<<<NPOSTS / 8, 256, 0, stream>>>(uebuf, Wfold, bias3A, bpart, s2v);

    // ---- stage 2 ----
    k_gemm1<<<dim3(NPOSTS / 16, 2), 256, 0, stream>>>(s2v, td_w1, bu_w1, td_b1, bu_b1, deg,
                                                      hbuf, cbuf);
    k_scat<<<dim3(NEDGE, 2), 256, 0, stream>>>(eiTD, eiBU, hbuf, deg, cbuf);

    k_root<<<dim3(1, 2), 256, 0, stream>>>(s2v, cbuf, td_w2, bu_w2, threadIdxP, rootv, c1root);

    k_gemm2<<<dim3(NPOSTS / 16, 2), 256, 0, stream>>>(cbuf, td_w2, bu_w2, td_b2, bu_b2, deg,
                                                      rootv, hbuf, cbuf);
    k_scat<<<dim3(NEDGE, 2), 256, 0, stream>>>(eiTD, eiBU, hbuf, deg, cbuf);

    k_reduce<<<dim3(NPOSTS / 32, 2), 256, 0, stream>>>(cbuf, msum);

    k_final<<<1, 256, 0, stream>>>(c1root, msum, fc_w, fc_b, outp);
}

// Round 6
// 354.851 us; speedup vs baseline: 1.0659x; 1.0659x over previous
//
#include <hip/hip_runtime.h>

#define NPOSTS 2048
#define SEQ 64
#define W2V 300
#define NH 5
#define HD 60
#define S2VD 256
#define HIDD 256
#define NEDGE 2047
#define UDIM 1500

#define GLOAD_LDS(g, l) \
    __builtin_amdgcn_global_load_lds((const __attribute__((address_space(1))) void*)(g), \
                                     (__attribute__((address_space(3))) void*)(l), 16, 0, 0)

// ================= Stage 0a: WsWo = Ws@Wo [256x300]; bias3A = bs + Ws@bo =================
__global__ __launch_bounds__(320) void k_wfoldA(
    const float* __restrict__ Ws, const float* __restrict__ Wo,
    const float* __restrict__ bo, const float* __restrict__ bs,
    float* __restrict__ WsWo, float* __restrict__ bias3A)
{
    const int r0 = blockIdx.x * 16;
    const int tid = threadIdx.x;
    __shared__ float sT[W2V][16];   // sT[k][r] = Ws[r0+r][k]
    for (int i = tid; i < 16 * W2V; i += 320) {
        int r = i / W2V, k = i % W2V;
        sT[k][r] = Ws[(size_t)(r0 + r) * W2V + k];
    }
    __syncthreads();
    if (tid <= W2V) {
        float a[16];
        #pragma unroll
        for (int r = 0; r < 16; ++r) a[r] = 0.f;
        for (int k = 0; k < W2V; ++k) {
            float wv = (tid < W2V) ? Wo[(size_t)k * W2V + tid] : bo[k];
            const float4* s4 = reinterpret_cast<const float4*>(&sT[k][0]);
            float4 q0 = s4[0], q1 = s4[1], q2 = s4[2], q3 = s4[3];
            float qq[16] = {q0.x,q0.y,q0.z,q0.w, q1.x,q1.y,q1.z,q1.w,
                            q2.x,q2.y,q2.z,q2.w, q3.x,q3.y,q3.z,q3.w};
            #pragma unroll
            for (int r = 0; r < 16; ++r) a[r] = fmaf(wv, qq[r], a[r]);
        }
        if (tid < W2V) {
            #pragma unroll
            for (int r = 0; r < 16; ++r) WsWo[(size_t)(r0 + r) * W2V + tid] = a[r];
        } else {
            #pragma unroll
            for (int r = 0; r < 16; ++r) bias3A[r0 + r] = bs[r0 + r] + a[r];
        }
    }
}

// ===== Stage 0b: Wfold[t][h*300+c] = sum_d WsWo[t][h*60+d]*Wv[600+h*60+d][c]; bpart = WsWo_h@bv_h =====
__global__ __launch_bounds__(320) void k_wfold2(
    const float* __restrict__ WsWo, const float* __restrict__ Wqkv, const float* __restrict__ bqkv,
    float* __restrict__ Wfold, float* __restrict__ bpart)
{
    const int r0 = blockIdx.x * 16;
    const int h = blockIdx.y;
    const int tid = threadIdx.x;
    __shared__ float sT[HD][16];    // sT[d][r] = WsWo[r0+r][h*60+d]
    for (int i = tid; i < 16 * HD; i += 320) {
        int r = i / HD, d = i % HD;
        sT[d][r] = WsWo[(size_t)(r0 + r) * W2V + h * HD + d];
    }
    __syncthreads();
    if (tid <= W2V) {
        float a[16];
        #pragma unroll
        for (int r = 0; r < 16; ++r) a[r] = 0.f;
        for (int d = 0; d < HD; ++d) {
            float wv = (tid < W2V) ? Wqkv[(size_t)(2 * W2V + h * HD + d) * W2V + tid]
                                   : bqkv[2 * W2V + h * HD + d];
            const float4* s4 = reinterpret_cast<const float4*>(&sT[d][0]);
            float4 q0 = s4[0], q1 = s4[1], q2 = s4[2], q3 = s4[3];
            float qq[16] = {q0.x,q0.y,q0.z,q0.w, q1.x,q1.y,q1.z,q1.w,
                            q2.x,q2.y,q2.z,q2.w, q3.x,q3.y,q3.z,q3.w};
            #pragma unroll
            for (int r = 0; r < 16; ++r) a[r] = fmaf(wv, qq[r], a[r]);
        }
        if (tid < W2V) {
            #pragma unroll
            for (int r = 0; r < 16; ++r)
                Wfold[(size_t)(r0 + r) * UDIM + h * W2V + tid] = a[r];
        } else {
            #pragma unroll
            for (int r = 0; r < 16; ++r) bpart[h * S2VD + r0 + r] = a[r];
        }
    }
}

// ================= Stage 1a: Q = Emb0 @ Wq^T + bq  (8 posts/block) =================
__global__ __launch_bounds__(320) void k_q(
    const int* __restrict__ nodeText, const float* __restrict__ embed_w,
    const float* __restrict__ Wqkv, const float* __restrict__ bqkv,
    float* __restrict__ Qout)
{
    const int r0 = blockIdx.x * 8;
    const int tid = threadIdx.x;
    __shared__ int stok[8];
    __shared__ float sE[8][W2V];
    if (tid < 8) stok[tid] = nodeText[(size_t)(r0 + tid) * SEQ];
    __syncthreads();
    for (int i = tid; i < 8 * 75; i += 320) {
        int r = i / 75, c4 = i % 75;
        *reinterpret_cast<float4*>(&sE[r][c4 * 4]) =
            *reinterpret_cast<const float4*>(embed_w + (size_t)stok[r] * W2V + c4 * 4);
    }
    __syncthreads();
    if (tid < W2V) {
        const float4* w4p = reinterpret_cast<const float4*>(Wqkv + (size_t)tid * W2V);
        float b = bqkv[tid];
        float a[8];
        #pragma unroll
        for (int r = 0; r < 8; ++r) a[r] = b;
        for (int c4 = 0; c4 < 75; ++c4) {
            float4 w4 = w4p[c4];
            #pragma unroll
            for (int r = 0; r < 8; ++r) {
                float4 v = *reinterpret_cast<const float4*>(&sE[r][c4 * 4]);
                a[r] = fmaf(w4.x, v.x, a[r]);
                a[r] = fmaf(w4.y, v.y, a[r]);
                a[r] = fmaf(w4.z, v.z, a[r]);
                a[r] = fmaf(w4.w, v.w, a[r]);
            }
        }
        #pragma unroll
        for (int r = 0; r < 8; ++r) Qout[(size_t)(r0 + r) * W2V + tid] = a[r];
    }
}

// ================= Stage 1b: u[p][h*300+c] = sum_d Q[p][h*60+d] * Wk[300+h*60+d][c] =================
__global__ __launch_bounds__(320) void k_u(
    const float* __restrict__ Q, const float* __restrict__ Wqkv, float* __restrict__ uout)
{
    const int r0 = blockIdx.x * 16;
    const int h = blockIdx.y;
    const int tid = threadIdx.x;
    __shared__ float sT[HD][16];   // sT[d][r] = Q[r0+r][h*60+d]
    for (int i = tid; i < 16 * HD; i += 320) {
        int r = i / HD, d = i % HD;
        sT[d][r] = Q[(size_t)(r0 + r) * W2V + h * HD + d];
    }
    __syncthreads();
    if (tid < W2V) {
        float a[16];
        #pragma unroll
        for (int r = 0; r < 16; ++r) a[r] = 0.f;
        for (int d = 0; d < HD; ++d) {
            float wv = Wqkv[(size_t)(W2V + h * HD + d) * W2V + tid];   // coalesced
            const float4* s4 = reinterpret_cast<const float4*>(&sT[d][0]);
            float4 q0 = s4[0], q1 = s4[1], q2 = s4[2], q3 = s4[3];
            float qq[16] = {q0.x,q0.y,q0.z,q0.w, q1.x,q1.y,q1.z,q1.w,
                            q2.x,q2.y,q2.z,q2.w, q3.x,q3.y,q3.z,q3.w};
            #pragma unroll
            for (int r = 0; r < 16; ++r) a[r] = fmaf(wv, qq[r], a[r]);
        }
        #pragma unroll
        for (int r = 0; r < 16; ++r)
            uout[(size_t)(r0 + r) * UDIM + h * W2V + tid] = a[r];
    }
}

// ===== Stage 1c: scores + softmax + e; 2 posts/block, async global_load_lds Emb staging =====
__global__ __launch_bounds__(512) void k_att(
    const int* __restrict__ nodeText, const float* __restrict__ embed_w,
    float* __restrict__ ue)
{
    __shared__ float sE[2 * SEQ * W2V];    // 153600 B flat (DMA dest must be linear)
    __shared__ float satt[2][NH][SEQ];     // 2560 B
    __shared__ int   stoks[2][SEQ];        // 512 B

    const int p0 = blockIdx.x * 2;
    const int tid = threadIdx.x;
    const int wave = tid >> 6, lane = tid & 63;

    if (tid < 2 * SEQ) stoks[tid >> 6][tid & 63] = nodeText[(size_t)p0 * SEQ + tid];
    __syncthreads();

    // async DMA: 9600 float4-chunks; chunk i -> sE[4i..4i+3]
    // i -> pp = i/4800, idx = i%4800, row = idx/75, c4 = idx%75  (16B never crosses a row: 300%4==0)
    #pragma unroll 3
    for (int it = 0; it < 18; ++it) {
        int i = it * 512 + tid;
        int pp = i / 4800, idx = i % 4800;
        int row = idx / 75, c4 = idx - row * 75;
        const float* src = embed_w + (size_t)stoks[pp][row] * W2V + c4 * 4;
        GLOAD_LDS(src, &sE[i * 4]);
    }
    if (wave < 6) {   // tail: 384 chunks, wave-uniform predicate (no intra-wave divergence)
        int i = 18 * 512 + tid;
        int pp = i / 4800, idx = i % 4800;
        int row = idx / 75, c4 = idx - row * 75;
        const float* src = embed_w + (size_t)stoks[pp][row] * W2V + c4 * 4;
        GLOAD_LDS(src, &sE[i * 4]);
    }
    asm volatile("s_waitcnt vmcnt(0)" ::: "memory");
    __syncthreads();

    // scores: 10 (post,head) tasks on 8 waves; lane j = token j; u wave-uniform (scalarizable)
    const float SC = 0.12909944487358056f;  // 60^-0.5
    for (int task = wave; task < 2 * NH; task += 8) {
        int pp = task / NH, h = task - pp * NH;
        const float4* u4 = reinterpret_cast<const float4*>(ue + (size_t)(p0 + pp) * UDIM + h * W2V);
        const float* er = &sE[(pp * SEQ + lane) * W2V];
        float acc = 0.f;
        #pragma unroll 5
        for (int c4 = 0; c4 < 75; ++c4) {
            float4 uv = u4[c4];
            float4 ev = *reinterpret_cast<const float4*>(er + c4 * 4);
            acc = fmaf(uv.x, ev.x, acc);
            acc = fmaf(uv.y, ev.y, acc);
            acc = fmaf(uv.z, ev.z, acc);
            acc = fmaf(uv.w, ev.w, acc);
        }
        // |score| << 1 by construction (0.02-scale weights) -> exp safe without max-subtract
        float ex = expf(acc * SC);
        float l = ex;
        #pragma unroll
        for (int off = 32; off > 0; off >>= 1) l += __shfl_xor(l, off);
        satt[pp][h][lane] = ex / l;
    }
    __syncthreads();

    // e[pp][h][c] = sum_j att[pp][h][j] * Emb[pp][j][c]; 750 float4-tasks over 512 threads
    for (int t = tid; t < 2 * NH * 75; t += 512) {
        int pp = t / 375, r = t - pp * 375;
        int h = r / 75, c4 = r - h * 75;
        const float* att = &satt[pp][h][0];
        const float* eb = &sE[pp * SEQ * W2V + c4 * 4];
        float4 a = make_float4(0.f, 0.f, 0.f, 0.f);
        #pragma unroll 4
        for (int j = 0; j < SEQ; ++j) {
            float av = att[j];
            float4 ev = *reinterpret_cast<const float4*>(eb + j * W2V);
            a.x = fmaf(av, ev.x, a.x);
            a.y = fmaf(av, ev.y, a.y);
            a.z = fmaf(av, ev.z, a.z);
            a.w = fmaf(av, ev.w, a.w);
        }
        *reinterpret_cast<float4*>(ue + (size_t)(p0 + pp) * UDIM + h * W2V + c4 * 4) = a;
    }
}

// ================= Stage 1d: s2v = tanh(Wfold @ e + bias3)  (8 posts/block, K=1500) =================
__global__ __launch_bounds__(256) void k_s2v(
    const float* __restrict__ e, const float* __restrict__ Wfold,
    const float* __restrict__ bias3A, const float* __restrict__ bpart,
    float* __restrict__ s2v_out)
{
    const int r0 = blockIdx.x * 8;
    const int t = threadIdx.x;
    __shared__ float se[8][W2V];
    float a[8];
    #pragma unroll
    for (int r = 0; r < 8; ++r) a[r] = 0.f;
    const float bias = bias3A[t] + bpart[t] + bpart[256 + t] + bpart[512 + t]
                     + bpart[768 + t] + bpart[1024 + t];
    const float4* w4p = reinterpret_cast<const float4*>(Wfold + (size_t)t * UDIM);
    for (int ch = 0; ch < 5; ++ch) {
        __syncthreads();
        for (int i = t; i < 8 * 75; i += 256) {
            int r = i / 75, c4 = i % 75;
            *reinterpret_cast<float4*>(&se[r][c4 * 4]) =
                *reinterpret_cast<const float4*>(e + (size_t)(r0 + r) * UDIM + ch * W2V + c4 * 4);
        }
        __syncthreads();
        for (int c4 = 0; c4 < 75; ++c4) {
            float4 w4 = w4p[ch * 75 + c4];
            #pragma unroll
            for (int r = 0; r < 8; ++r) {
                float4 v = *reinterpret_cast<const float4*>(&se[r][c4 * 4]);
                a[r] = fmaf(w4.x, v.x, a[r]);
                a[r] = fmaf(w4.y, v.y, a[r]);
                a[r] = fmaf(w4.z, v.z, a[r]);
                a[r] = fmaf(w4.w, v.w, a[r]);
            }
        }
    }
    #pragma unroll
    for (int r = 0; r < 8; ++r)
        s2v_out[(size_t)(r0 + r) * S2VD + t] = tanhf(a[r] + bias);
}

// ================= Stage 2: GCN branches (blockIdx.y = branch: 0=TD, 1=BU) =================

__global__ __launch_bounds__(256) void k_deg(
    const int* __restrict__ eiTD, const int* __restrict__ eiBU, int* __restrict__ deg)
{
    const int b = blockIdx.y;
    const int* ei = b ? eiBU : eiTD;
    int e = blockIdx.x * 256 + threadIdx.x;
    if (e < NEDGE) atomicAdd(&deg[b * NPOSTS + ei[NEDGE + e]], 1);
}

__global__ __launch_bounds__(256) void k_gemm1(
    const float* __restrict__ x, const float* __restrict__ wtd, const float* __restrict__ wbu,
    const float* __restrict__ btd, const float* __restrict__ bbu, const int* __restrict__ deg,
    float* __restrict__ hout, float* __restrict__ cout_)
{
    const int b = blockIdx.y;
    const float* w = b ? wbu : wtd;
    const float* bias = b ? bbu : btd;
    float* hb = hout + (size_t)b * NPOSTS * HIDD;
    float* cb = cout_ + (size_t)b * NPOSTS * HIDD;
    const int* dg = deg + b * NPOSTS;
    const int r0 = blockIdx.x * 16;
    const int tid = threadIdx.x;
    __shared__ float sx[16][S2VD];
    for (int i = tid; i < 16 * S2VD; i += 256)
        sx[i / S2VD][i % S2VD] = x[(size_t)(r0 + i / S2VD) * S2VD + (i % S2VD)];
    __syncthreads();
    float acc[16];
    #pragma unroll
    for (int r = 0; r < 16; ++r) acc[r] = 0.f;
    const float4* wr4 = reinterpret_cast<const float4*>(w + (size_t)tid * S2VD);
    for (int c4 = 0; c4 < 64; ++c4) {
        float4 w4 = wr4[c4];
        #pragma unroll
        for (int r = 0; r < 16; ++r) {
            const float4 v = *reinterpret_cast<const float4*>(&sx[r][c4 * 4]);
            acc[r] = fmaf(w4.x, v.x, acc[r]);
            acc[r] = fmaf(w4.y, v.y, acc[r]);
            acc[r] = fmaf(w4.z, v.z, acc[r]);
            acc[r] = fmaf(w4.w, v.w, acc[r]);
        }
    }
    float bv = bias[tid];
    #pragma unroll
    for (int r = 0; r < 16; ++r) {
        int n = r0 + r;
        float dinv = 1.f / (float)(dg[n] + 1);
        hb[(size_t)n * HIDD + tid] = acc[r];
        cb[(size_t)n * HIDD + tid] = bv + acc[r] * dinv;
    }
}

__global__ __launch_bounds__(256) void k_gemm2(
    const float* __restrict__ c1, const float* __restrict__ w2td, const float* __restrict__ w2bu,
    const float* __restrict__ btd, const float* __restrict__ bbu, const int* __restrict__ deg,
    const float* __restrict__ rootv, float* __restrict__ hout, float* __restrict__ cout_)
{
    const int b = blockIdx.y;
    const float* w = b ? w2bu : w2td;
    const float* bias = b ? bbu : btd;
    const float* xin = c1 + (size_t)b * NPOSTS * HIDD;
    float* hb = hout + (size_t)b * NPOSTS * HIDD;
    float* cb = cout_ + (size_t)b * NPOSTS * HIDD;
    const int* dg = deg + b * NPOSTS;
    const int r0 = blockIdx.x * 16;
    const int tid = threadIdx.x;
    __shared__ float sx[16][HIDD];
    for (int i = tid; i < 16 * HIDD; i += 256)
        sx[i / HIDD][i % HIDD] = fmaxf(xin[(size_t)(r0 + i / HIDD) * HIDD + (i % HIDD)], 0.f);
    __syncthreads();
    float acc[16];
    const float rv = rootv[b * HIDD + tid];
    #pragma unroll
    for (int r = 0; r < 16; ++r) acc[r] = rv;
    const float4* wr4 = reinterpret_cast<const float4*>(w + (size_t)tid * 512);
    for (int c4 = 0; c4 < 64; ++c4) {
        float4 w4 = wr4[c4];
        #pragma unroll
        for (int r = 0; r < 16; ++r) {
            const float4 v = *reinterpret_cast<const float4*>(&sx[r][c4 * 4]);
            acc[r] = fmaf(w4.x, v.x, acc[r]);
            acc[r] = fmaf(w4.y, v.y, acc[r]);
            acc[r] = fmaf(w4.z, v.z, acc[r]);
            acc[r] = fmaf(w4.w, v.w, acc[r]);
        }
    }
    float bv = bias[tid];
    #pragma unroll
    for (int r = 0; r < 16; ++r) {
        int n = r0 + r;
        float dinv = 1.f / (float)(dg[n] + 1);
        hb[(size_t)n * HIDD + tid] = acc[r];
        cb[(size_t)n * HIDD + tid] = bv + acc[r] * dinv;
    }
}

__global__ __launch_bounds__(256) void k_scat(
    const int* __restrict__ eiTD, const int* __restrict__ eiBU,
    const float* __restrict__ h, const int* __restrict__ deg, float* __restrict__ cacc)
{
    const int b = blockIdx.y, e = blockIdx.x, tid = threadIdx.x;
    const int* ei = b ? eiBU : eiTD;
    const int s = ei[e], d = ei[NEDGE + e];
    const int* dg = deg + b * NPOSTS;
    float norm = rsqrtf((float)(dg[s] + 1)) * rsqrtf((float)(dg[d] + 1));
    const float* hb = h + (size_t)b * NPOSTS * HIDD;
    float* cb = cacc + (size_t)b * NPOSTS * HIDD;
    atomicAdd(&cb[(size_t)d * HIDD + tid], norm * hb[(size_t)s * HIDD + tid]);
}

__global__ __launch_bounds__(256) void k_root(
    const float* __restrict__ s2v, const float* __restrict__ c1,
    const float* __restrict__ w2td, const float* __restrict__ w2bu,
    const int* __restrict__ rootPtr, float* __restrict__ rootv, float* __restrict__ c1root)
{
    const int b = blockIdx.y, tid = threadIdx.x;
    const float* w2 = b ? w2bu : w2td;
    const int root = rootPtr[0];
    __shared__ float sx[S2VD];
    sx[tid] = fmaxf(s2v[(size_t)root * S2VD + tid], 0.f);
    __syncthreads();
    const float* cb = c1 + (size_t)b * NPOSTS * HIDD;
    c1root[b * HIDD + tid] = cb[(size_t)root * HIDD + tid];
    const float* wr = w2 + (size_t)tid * 512 + 256;
    float acc = 0.f;
    #pragma unroll 4
    for (int c = 0; c < S2VD; ++c) acc = fmaf(wr[c], sx[c], acc);
    rootv[b * HIDD + tid] = acc;
}

__global__ __launch_bounds__(256) void k_reduce(
    const float* __restrict__ cacc, float* __restrict__ msum)
{
    const int b = blockIdx.y, tid = threadIdx.x;
    const int base = blockIdx.x * 32;
    const float* cb = cacc + (size_t)b * NPOSTS * HIDD;
    float local = 0.f;
    #pragma unroll 4
    for (int r = 0; r < 32; ++r) local += fmaxf(cb[(size_t)(base + r) * HIDD + tid], 0.f);
    atomicAdd(&msum[b * HIDD + tid], local);
}

__global__ __launch_bounds__(256) void k_final(
    const float* __restrict__ c1root, const float* __restrict__ msum,
    const float* __restrict__ fc_w, const float* __restrict__ fc_b, float* __restrict__ outp)
{
    const int tid = threadIdx.x;
    __shared__ float sf[1024];
    for (int k = tid; k < 1024; k += 256) {
        int seg = k >> 8, idx = k & 255;
        float v;
        if (seg == 0)      v = c1root[idx];
        else if (seg == 1) v = msum[idx] * (1.f / (float)NPOSTS);
        else if (seg == 2) v = c1root[256 + idx];
        else               v = msum[256 + idx] * (1.f / (float)NPOSTS);
        sf[k] = v;
    }
    __syncthreads();
    const int t = tid >> 6, lane = tid & 63;
    float part = 0.f;
    for (int k = lane; k < 1024; k += 64) part = fmaf(fc_w[t * 1024 + k], sf[k], part);
    #pragma unroll
    for (int off = 32; off > 0; off >>= 1) part += __shfl_down(part, off);
    if (lane == 0) outp[t] = part + fc_b[t];
}

extern "C" void kernel_launch(void* const* d_in, const int* in_sizes, int n_in,
                              void* d_out, int out_size, void* d_ws, size_t ws_size,
                              hipStream_t stream) {
    (void)in_sizes; (void)n_in; (void)out_size; (void)ws_size;

    const int*   nodeText   = (const int*)d_in[0];
    const int*   eiTD       = (const int*)d_in[1];
    const int*   eiBU       = (const int*)d_in[2];
    const int*   threadIdxP = (const int*)d_in[3];
    const float* embed_w    = (const float*)d_in[5];
    const float* in_proj_w  = (const float*)d_in[6];
    const float* in_proj_b  = (const float*)d_in[7];
    const float* out_proj_w = (const float*)d_in[8];
    const float* out_proj_b = (const float*)d_in[9];
    const float* s2v_w      = (const float*)d_in[10];
    const float* s2v_b      = (const float*)d_in[11];
    const float* td_w1      = (const float*)d_in[12];
    const float* td_b1      = (const float*)d_in[13];
    const float* td_w2      = (const float*)d_in[14];
    const float* td_b2      = (const float*)d_in[15];
    const float* bu_w1      = (const float*)d_in[16];
    const float* bu_b1      = (const float*)d_in[17];
    const float* bu_w2      = (const float*)d_in[18];
    const float* bu_b2      = (const float*)d_in[19];
    const float* fc_w       = (const float*)d_in[20];
    const float* fc_b       = (const float*)d_in[21];
    float* outp = (float*)d_out;

    // workspace layout
    char* w = (char*)d_ws;
    int*   deg    = (int*)w;                                          // 16384 B
    float* msum   = (float*)(w + 16384);                              // 2048 B
    float* rootv  = (float*)(w + 16384 + 2048);
    float* c1root = (float*)(w + 16384 + 4096);
    float* s2v    = (float*)(w + 24576);                              // 2 MB
    float* hbuf   = (float*)(w + 24576 + 2097152);                    // 4 MB
    float* cbuf   = (float*)(w + 24576 + 2097152 + 4194304);          // 4 MB
    float* Qbuf   = (float*)(w + 24576 + 2097152 + 4194304 + 4194304);             // 2.46 MB
    float* uebuf  = (float*)(w + 24576 + 2097152 + 4194304 + 4194304 + 2457600);   // 12.29 MB

    // folded-weight buffers alias hbuf/cbuf (consumed before k_gemm1 writes them)
    float* Wfold  = hbuf;                 // 256*1500 floats = 1.536 MB
    float* WsWo   = cbuf;                 // 256*300 floats
    float* bias3A = cbuf + 256 * 300;     // 256 floats
    float* bpart  = bias3A + 256;         // 5*256 floats

    hipMemsetAsync(d_ws, 0, 16384 + 2048, stream);

    // ---- independent prep ----
    k_deg<<<dim3((NEDGE + 255) / 256, 2), 256, 0, stream>>>(eiTD, eiBU, deg);
    k_wfoldA<<<16, 320, 0, stream>>>(s2v_w, out_proj_w, out_proj_b, s2v_b, WsWo, bias3A);
    k_wfold2<<<dim3(16, 5), 320, 0, stream>>>(WsWo, in_proj_w, in_proj_b, Wfold, bpart);

    // ---- stage 1 ----
    k_q  <<<NPOSTS / 8, 320, 0, stream>>>(nodeText, embed_w, in_proj_w, in_proj_b, Qbuf);
    k_u  <<<dim3(NPOSTS / 16, 5), 320, 0, stream>>>(Qbuf, in_proj_w, uebuf);
    k_att<<<NPOSTS / 2, 512, 0, stream>>>(nodeText, embed_w, uebuf);
    k_s2v<<<NPOSTS / 8, 256, 0, stream>>>(uebuf, Wfold, bias3A, bpart, s2v);

    // ---- stage 2 ----
    k_gemm1<<<dim3(NPOSTS / 16, 2), 256, 0, stream>>>(s2v, td_w1, bu_w1, td_b1, bu_b1, deg,
                                                      hbuf, cbuf);
    k_scat<<<dim3(NEDGE, 2), 256, 0, stream>>>(eiTD, eiBU, hbuf, deg, cbuf);

    k_root<<<dim3(1, 2), 256, 0, stream>>>(s2v, cbuf, td_w2, bu_w2, threadIdxP, rootv, c1root);

    k_gemm2<<<dim3(NPOSTS / 16, 2), 256, 0, stream>>>(cbuf, td_w2, bu_w2, td_b2, bu_b2, deg,
                                                      rootv, hbuf, cbuf);
    k_scat<<<dim3(NEDGE, 2), 256, 0, stream>>>(eiTD, eiBU, hbuf, deg, cbuf);

    k_reduce<<<dim3(NPOSTS / 32, 2), 256, 0, stream>>>(cbuf, msum);

    k_final<<<1, 256, 0, stream>>>(c1root, msum, fc_w, fc_b, outp);
}